// Round 17
// baseline (187.033 us; speedup 1.0000x reference)
//
#include <hip/hip_runtime.h>
#include <math.h>

#define SEQ 197
#define EMB 768
#define NH  12
#define HD  64
#define NE  28
#define SK  208
#define VP  232
#define PP  232
#define EP  232
#define HP  66
#define TP  66
#define NW  7
#define NT  448

typedef __attribute__((ext_vector_type(8))) __bf16 bf16x8;
typedef __attribute__((ext_vector_type(4))) float  f32x4;

__device__ __forceinline__ unsigned short f2bf(float f) {
    unsigned u = __float_as_uint(f);
    u += 0x7fffu + ((u >> 16) & 1u);
    return (unsigned short)(u >> 16);
}
__device__ __forceinline__ float bfl(unsigned u) { return __uint_as_float(u << 16); }

__device__ __forceinline__ void gl_lds16(const ushort* g, ushort* l) {
    __builtin_amdgcn_global_load_lds(
        (const __attribute__((address_space(1))) unsigned int*)g,
        (__attribute__((address_space(3))) unsigned int*)l, 16, 0, 0);
}

// ---------------------------------------------------------------------------
// prep kernels
// ---------------------------------------------------------------------------
__global__ void cvt_k(const float* __restrict__ src, ushort* __restrict__ dst, int n4) {
    int i = blockIdx.x * 256 + threadIdx.x;
    if (i < n4) {
        float4 v = ((const float4*)src)[i];
        ushort4 o = { f2bf(v.x), f2bf(v.y), f2bf(v.z), f2bf(v.w) };
        ((ushort4*)dst)[i] = o;
    }
}

__global__ void cvt_w4(const float* __restrict__ wq, const float* __restrict__ wk,
                       const float* __restrict__ wv, const float* __restrict__ wo,
                       ushort* __restrict__ wqkv, ushort* __restrict__ wob) {
    int i = blockIdx.x * 256 + threadIdx.x;
    if (i >= 4 * 147456) return;
    int seg = i / 147456, r = i - seg * 147456;
    const float* s = (seg == 0) ? wq : (seg == 1) ? wk : (seg == 2) ? wv : wo;
    float4 v = ((const float4*)s)[r];
    ushort4 o = { f2bf(v.x), f2bf(v.y), f2bf(v.z), f2bf(v.w) };
    if (seg < 3) ((ushort4*)wqkv)[(size_t)seg * 147456 + r] = o;
    else         ((ushort4*)wob)[r] = o;
}

// ---------------------------------------------------------------------------
// rxy via tiny MFMA GEMM (r15) — unchanged.
// ---------------------------------------------------------------------------
__global__ __launch_bounds__(256) void rxy_gemm(
    const ushort* __restrict__ xq,
    const float* __restrict__ qtx, const float* __restrict__ qty,
    ushort* __restrict__ r_o)
{
    __shared__ __align__(16) ushort qtab_s[64][66];

    const int bh = blockIdx.x;
    const size_t base = (size_t)bh * SEQ * HD;
    const int tid = threadIdx.x;
    const int w = tid >> 6, lane = tid & 63;
    const int g = lane >> 4, c15 = lane & 15;

    for (int idx = tid; idx < 64 * 64; idx += 256) {
        const int e = idx >> 6, d = idx & 63;
        float v = 0.f;
        if (e < 28)      { if (d < 32)  v = qtx[e * 32 + d]; }
        else if (e < 56) { if (d >= 32) v = qty[(e - 28) * 32 + (d - 32)]; }
        qtab_s[e][d] = f2bf(v);
    }
    __syncthreads();

    for (int qt = w; qt < 13; qt += 4) {
        const int qrow = qt * 16 + c15;
        const int qld = (qrow < SEQ) ? qrow : SEQ - 1;
        const bf16x8 qa0 = *(const bf16x8*)(xq + base + (size_t)qld * HD + g * 8);
        const bf16x8 qa1 = *(const bf16x8*)(xq + base + (size_t)qld * HD + 32 + g * 8);
#pragma unroll
        for (int et = 0; et < 4; et++) {
            bf16x8 t0 = *(const bf16x8*)&qtab_s[et * 16 + c15][g * 8];
            bf16x8 t1 = *(const bf16x8*)&qtab_s[et * 16 + c15][32 + g * 8];
            f32x4 a = (f32x4)0.f;
            a = __builtin_amdgcn_mfma_f32_16x16x32_bf16(qa0, t0, a, 0, 0, 0);
            a = __builtin_amdgcn_mfma_f32_16x16x32_bf16(qa1, t1, a, 0, 0, 0);
#pragma unroll
            for (int r = 0; r < 4; r++) {
                const int q = qt * 16 + g * 4 + r;
                const int e = et * 16 + c15;
                if (q < SEQ && e < 56)
                    r_o[((size_t)bh * SEQ + q) * 56 + e] = f2bf(a[r]);
            }
        }
    }
}

// ---------------------------------------------------------------------------
// 128x128 GEMM, BK=64, DOUBLE-BUFFERED (r17, T3-minimum 2-phase):
// STAGE(t+1) issued BEFORE computing tile t; ONE __syncthreads per tile
// (its vmcnt drain waits on ~500cy-old loads -> nearly free). LDS 64 KB ->
// still 2 blocks/CU. Swizzled staging (linear dest + src^(row&7), read
// ^(row&7)) as r16. XCD-chunked grid swizzle retained.
// ---------------------------------------------------------------------------
template<int MODE>
__global__ __launch_bounds__(256, 2) void gemm_k64(
    const ushort* __restrict__ A, const ushort* __restrict__ W,
    const float* __restrict__ b0, const float* __restrict__ b1, const float* __restrict__ b2,
    ushort* __restrict__ q_o, ushort* __restrict__ k_o, ushort* __restrict__ v_o,
    float* __restrict__ f_o, int M)
{
    __shared__ __align__(16) ushort As[2][128 * 64];   // 2 x 16 KB
    __shared__ __align__(16) ushort Bs[2][128 * 64];

    const int tid  = threadIdx.x;
    const int w    = tid >> 6, lane = tid & 63;
    const int wr   = w >> 1,  wc   = w & 1;

    const int nmt = gridDim.x, nnt = gridDim.y;
    const int lin = blockIdx.y * nmt + blockIdx.x;
    const int gsz = 8 * nnt;
    const int grp = lin / gsz;
    const int rr  = lin - grp * gsz;
    int mig = nmt - grp * 8; if (mig > 8) mig = 8;
    const int mt  = grp * 8 + rr % mig;
    const int nt  = rr / mig;
    const int m0  = mt * 128;
    const int n0  = nt * 128;

    // staging granule map: g = tid + i*256 ; row = g>>3, chunk = g&7 (16B)
    int arow[4], asrc[4];
#pragma unroll
    for (int i = 0; i < 4; i++) {
        const int gidx = tid + i * 256;
        const int row = gidx >> 3, ch = gidx & 7;
        arow[i] = row;
        asrc[i] = (ch ^ (row & 7)) * 8;
    }

    f32x4 acc[4][4];
#pragma unroll
    for (int m = 0; m < 4; m++)
#pragma unroll
        for (int n = 0; n < 4; n++) acc[m][n] = (f32x4)0.f;

    auto STAGE = [&](int t) {
        const int buf = t & 1, k0 = t * 64;
#pragma unroll
        for (int i = 0; i < 4; i++) {
            int ra = m0 + arow[i]; if (ra >= M) ra = M - 1;
            gl_lds16(A + (size_t)ra * EMB + k0 + asrc[i], &As[buf][(tid + i * 256) * 8]);
            gl_lds16(W + (size_t)(n0 + arow[i]) * EMB + k0 + asrc[i], &Bs[buf][(tid + i * 256) * 8]);
        }
    };

    STAGE(0);
    __syncthreads();

    const int NKT = EMB / 64;   // 12
    for (int t = 0; t < NKT; ++t) {
        if (t + 1 < NKT) STAGE(t + 1);
        const ushort* Ab = As[t & 1];
        const ushort* Bb = Bs[t & 1];
#pragma unroll
        for (int kk = 0; kk < 2; kk++) {
            bf16x8 af[4], bfr[4];
#pragma unroll
            for (int m = 0; m < 4; m++) {
                const int row = wr * 64 + m * 16 + (lane & 15);
                af[m] = *(const bf16x8*)&Ab[row * 64 + (((kk * 4 + (lane >> 4)) ^ (row & 7)) << 3)];
            }
#pragma unroll
            for (int n = 0; n < 4; n++) {
                const int row = wc * 64 + n * 16 + (lane & 15);
                bfr[n] = *(const bf16x8*)&Bb[row * 64 + (((kk * 4 + (lane >> 4)) ^ (row & 7)) << 3)];
            }
#pragma unroll
            for (int m = 0; m < 4; m++)
#pragma unroll
                for (int n = 0; n < 4; n++)
                    acc[m][n] = __builtin_amdgcn_mfma_f32_16x16x32_bf16(af[m], bfr[n], acc[m][n], 0, 0, 0);
        }
        __syncthreads();
    }

    const int mat = n0 / EMB;
    const int nr  = n0 - mat * EMB;
    const float* bias = (mat == 0) ? b0 : (mat == 1) ? b1 : b2;
    ushort* dst = (mat == 0) ? q_o : (mat == 1) ? k_o : v_o;

#pragma unroll
    for (int m = 0; m < 4; m++) {
#pragma unroll
        for (int r = 0; r < 4; r++) {
            const int gm = m0 + wr * 64 + m * 16 + (lane >> 4) * 4 + r;
            if (gm >= M) continue;
            const int bb = gm / SEQ, ss = gm - bb * SEQ;
#pragma unroll
            for (int n = 0; n < 4; n++) {
                const int col = nr + wc * 64 + n * 16 + (lane & 15);
                if (MODE == 0) {
                    const float v = acc[m][n][r] + bias[col];
                    dst[(((size_t)bb * NH + (col >> 6)) * SEQ + ss) * HD + (col & 63)] = f2bf(v);
                } else {
                    f_o[(size_t)gm * EMB + col] = acc[m][n][r] + b0[col];
                }
            }
        }
    }
}

// ---------------------------------------------------------------------------
// MFMA fused attention (r12 one-hot factorization) + r17 latency trims:
// cx/cy staged packed in LDS (no global dist reads in main loop); P_s pad-
// only zeroing; HP=66.
// ---------------------------------------------------------------------------
__global__ __launch_bounds__(NT) void attn_mfma(
    const ushort* __restrict__ xq, const ushort* __restrict__ xk, const ushort* __restrict__ xv,
    const ushort* __restrict__ rxy_g,
    const float* __restrict__ v_tab_x, const float* __restrict__ v_tab_y,
    const int* __restrict__ x_dist, const int* __restrict__ y_dist,
    ushort* __restrict__ ao)
{
    __shared__ __align__(16) ushort K_s[SK * HD];        // 26624 B
    __shared__ __align__(16) ushort EXYs_s[SK * 40];     // 16640 B
    __shared__ __align__(16) ushort EXYT_s[32 * EP];     // 14848 B
    __shared__ __align__(16) ushort VT_s[HD * VP];       // 29696 B
    __shared__ __align__(16) ushort P_s[NW * 16 * PP];   // 51968 B
    __shared__ __align__(16) ushort vt_s[HD * TP];       // 8448 B
    __shared__ __align__(16) ushort h_s[NW][16][HP];     // 14784 B
    __shared__ ushort cxy_s[SEQ];                        // 394 B  -> 163402 total

    const int bh = blockIdx.x;
    const int b  = bh / NH;
    const int h  = bh % NH;
    const size_t base = (size_t)bh * SEQ * HD;
    const ushort* __restrict__ rxy_b = rxy_g + (size_t)bh * SEQ * 56;
    const int tid = threadIdx.x;
    const int w = tid >> 6, lane = tid & 63;
    const int g = lane >> 4, c15 = lane & 15;

    for (int idx = tid; idx < SK * 8; idx += NT) {
        const int r = idx >> 3, c = idx & 7;
        uint4 v = make_uint4(0, 0, 0, 0);
        if (r < SEQ) v = *(const uint4*)(xk + base + r * HD + c * 8);
        *(uint4*)&K_s[r * HD + ((c ^ (r & 7)) << 3)] = v;
    }
    for (int idx = tid; idx < SK * 40 / 8; idx += NT)
        *(uint4*)&EXYs_s[idx * 8] = make_uint4(0, 0, 0, 0);
    for (int idx = tid; idx < 32 * EP / 8; idx += NT)
        *(uint4*)&EXYT_s[idx * 8] = make_uint4(0, 0, 0, 0);
    for (int idx = tid; idx < HD * (VP - SEQ); idx += NT) {
        const int d = idx / (VP - SEQ), k = SEQ + idx - d * (VP - SEQ);
        VT_s[d * VP + k] = 0;
    }
    // P_s: zero only pad cols [208, PP) of all 112 rows (3 x 16B per row)
    for (int idx = tid; idx < NW * 16 * 3; idx += NT) {
        const int row = idx / 3, c = idx - row * 3;
        *(uint4*)&P_s[row * PP + 208 + c * 8] = make_uint4(0, 0, 0, 0);
    }
    // cx/cy packed (raw table values; row 1 of dist = distances to k, col0=0)
    for (int k = tid; k < SEQ; k += NT)
        cxy_s[k] = (ushort)((x_dist[SEQ + k] & 0xff) | ((y_dist[SEQ + k] & 0xff) << 8));
    for (int idx = tid; idx < 16 * 8 * 13; idx += NT) {
        const int kq = idx & 15, t = idx >> 4;
        const int db = t & 7, kh = t >> 3;
        const int k = kh * 16 + kq;
        if (k >= SEQ) continue;
        uint4 v = *(const uint4*)(xv + base + k * HD + db * 8);
        ushort* col = &VT_s[(db * 8) * VP + k];
        col[0 * VP] = (ushort)(v.x); col[1 * VP] = (ushort)(v.x >> 16);
        col[2 * VP] = (ushort)(v.y); col[3 * VP] = (ushort)(v.y >> 16);
        col[4 * VP] = (ushort)(v.z); col[5 * VP] = (ushort)(v.z >> 16);
        col[6 * VP] = (ushort)(v.w); col[7 * VP] = (ushort)(v.w >> 16);
    }
    for (int idx = tid; idx < HD * 64; idx += NT) {
        const int d = idx >> 6, e = idx & 63;
        float v = 0.f;
        if (d < 32) { if (e < 28) v = v_tab_x[e * 32 + d]; }
        else        { if (e >= 28 && e < 56) v = v_tab_y[(e - 28) * 32 + (d - 32)]; }
        vt_s[d * TP + e] = f2bf(v);
    }
    __syncthreads();
    for (int k = tid; k < SEQ; k += NT) {
        const int cx = (k == 0) ? 14 : ((cxy_s[k] & 0xff) - 14);
        const int cy = (k == 0) ? 14 : ((cxy_s[k] >> 8) - 14);
        const ushort one = 0x3f80;
        EXYs_s[k * 40 + cx]        = one;
        EXYs_s[k * 40 + 16 + cy]   = one;
        EXYT_s[cx * EP + k]        = one;
        EXYT_s[(16 + cy) * EP + k] = one;
    }
    __syncthreads();

    for (int qt = w; qt < 13; qt += NW) {
        const int qrow = qt * 16 + c15;
        const int qld  = (qrow < SEQ) ? qrow : (SEQ - 1);
        const bf16x8 qa0 = *(const bf16x8*)(xq + base + (size_t)qld * HD + g * 8);
        const bf16x8 qa1 = *(const bf16x8*)(xq + base + (size_t)qld * HD + 32 + g * 8);

        uint4 up;
        {
            const ushort* rrow = rxy_b + qld * 56;
            const int cxq = (qld > 0) ? ((cxy_s[qld] & 0xff) - 14) : 0;
            const int cyq = (qld > 0) ? ((cxy_s[qld] >> 8) - 14) : 0;
            unsigned uu[4] = {0, 0, 0, 0};
#pragma unroll
            for (int j = 0; j < 8; j++) {
                const int c = g * 8 + j;
                ushort v;
                if (qld == 0)      v = (c == 15 || c == 31) ? (ushort)0 : rrow[(c < 16) ? 0 : 28];
                else if (c < 14)   v = rrow[c - cxq + 14];
                else if (c == 14)  v = rrow[0];
                else if (c == 15)  v = 0;
                else if (c < 30)   v = rrow[28 + (c - 16) - cyq + 14];
                else if (c == 30)  v = rrow[28];
                else               v = 0;
                uu[j >> 1] |= ((unsigned)v) << ((j & 1) * 16);
            }
            up.x = uu[0]; up.y = uu[1]; up.z = uu[2]; up.w = uu[3];
        }
        const bf16x8 qa2 = *(bf16x8*)&up;

        {
            uint4* hz = (uint4*)h_s[w];
            for (int i = lane; i < 16 * HP / 8; i += 64) hz[i] = make_uint4(0, 0, 0, 0);
        }

        const int q4 = qt * 16 + 4 * g;
        float sum[4] = {0.f, 0.f, 0.f, 0.f};

#pragma unroll
        for (int kt = 0; kt < 13; kt++) {
            const int kr = kt * 16 + c15;
            bf16x8 kf0 = *(const bf16x8*)&K_s[kr * HD + (((0 + g) ^ (kr & 7)) << 3)];
            bf16x8 kf1 = *(const bf16x8*)&K_s[kr * HD + (((4 + g) ^ (kr & 7)) << 3)];
            bf16x8 kf2 = *(const bf16x8*)&EXYs_s[kr * 40 + g * 8];
            f32x4 a = (f32x4)0.f;
            a = __builtin_amdgcn_mfma_f32_16x16x32_bf16(qa0, kf0, a, 0, 0, 0);
            a = __builtin_amdgcn_mfma_f32_16x16x32_bf16(qa1, kf1, a, 0, 0, 0);
            a = __builtin_amdgcn_mfma_f32_16x16x32_bf16(qa2, kf2, a, 0, 0, 0);
#pragma unroll
            for (int r = 0; r < 4; r++) {
                const float l = a[r] * 0.125f - 8.0f;
                const float p = (kr < SEQ) ? __expf(l) : 0.f;
                sum[r] += p;
                P_s[(w * 16 + 4 * g + r) * PP + kr] = f2bf(p);
            }
        }
        float inv[4];
#pragma unroll
        for (int r = 0; r < 4; r++) {
            sum[r] += __shfl_xor(sum[r], 1);
            sum[r] += __shfl_xor(sum[r], 2);
            sum[r] += __shfl_xor(sum[r], 4);
            sum[r] += __shfl_xor(sum[r], 8);
            inv[r] = 1.f / sum[r];
        }

        f32x4 px0 = (f32x4)0.f, px1 = (f32x4)0.f;
#pragma unroll
        for (int ks = 0; ks < 7; ks++) {
            bf16x8 pf = *(const bf16x8*)&P_s[(w * 16 + c15) * PP + ks * 32 + g * 8];
            bf16x8 e0 = *(const bf16x8*)&EXYT_s[c15 * EP + ks * 32 + g * 8];
            bf16x8 e1 = *(const bf16x8*)&EXYT_s[(16 + c15) * EP + ks * 32 + g * 8];
            px0 = __builtin_amdgcn_mfma_f32_16x16x32_bf16(pf, e0, px0, 0, 0, 0);
            px1 = __builtin_amdgcn_mfma_f32_16x16x32_bf16(pf, e1, px1, 0, 0, 0);
        }

        float sx = px0[0], sy = px1[0];
        if (qt == 0) {
            sx += __shfl_xor(sx, 1); sx += __shfl_xor(sx, 2);
            sx += __shfl_xor(sx, 4); sx += __shfl_xor(sx, 8);
            sy += __shfl_xor(sy, 1); sy += __shfl_xor(sy, 2);
            sy += __shfl_xor(sy, 4); sy += __shfl_xor(sy, 8);
        }

#pragma unroll
        for (int r = 0; r < 4; r++) {
            const int q = q4 + r;
            if (q >= SEQ) continue;
            const int ql = 4 * g + r;
            if (q == 0) {
                if (c15 == 14) { h_s[w][ql][0] = f2bf(sx); h_s[w][ql][28] = f2bf(sy); }
            } else {
                const int cxq2 = (cxy_s[q] & 0xff) - 14;
                const int cyq2 = (cxy_s[q] >> 8) - 14;
                if (c15 < 14) {
                    h_s[w][ql][c15 - cxq2 + 14]      = f2bf(px0[r]);
                    h_s[w][ql][28 + c15 - cyq2 + 14] = f2bf(px1[r]);
                } else if (c15 == 14) {
                    h_s[w][ql][0]  = f2bf(px0[r]);
                    h_s[w][ql][28] = f2bf(px1[r]);
                }
            }
        }

        f32x4 o[4];
#pragma unroll
        for (int dt = 0; dt < 4; dt++) o[dt] = (f32x4)0.f;
#pragma unroll
        for (int ks = 0; ks < 7; ks++) {
            bf16x8 pf = *(const bf16x8*)&P_s[(w * 16 + c15) * PP + ks * 32 + g * 8];
#pragma unroll
            for (int dt = 0; dt < 4; dt++) {
                bf16x8 vf = *(const bf16x8*)&VT_s[(dt * 16 + c15) * VP + ks * 32 + g * 8];
                o[dt] = __builtin_amdgcn_mfma_f32_16x16x32_bf16(pf, vf, o[dt], 0, 0, 0);
            }
        }
#pragma unroll
        for (int ks2 = 0; ks2 < 2; ks2++) {
            bf16x8 hf = *(const bf16x8*)&h_s[w][c15][ks2 * 32 + g * 8];
#pragma unroll
            for (int dt = 0; dt < 4; dt++) {
                bf16x8 tf = *(const bf16x8*)&vt_s[(dt * 16 + c15) * TP + ks2 * 32 + g * 8];
                o[dt] = __builtin_amdgcn_mfma_f32_16x16x32_bf16(hf, tf, o[dt], 0, 0, 0);
            }
        }

#pragma unroll
        for (int dt = 0; dt < 4; dt++) {
            const int d = dt * 16 + c15;
#pragma unroll
            for (int r = 0; r < 4; r++) {
                const int q = q4 + r;
                if (q < SEQ)
                    ao[((size_t)(b * SEQ + q)) * EMB + h * HD + d] = f2bf(o[dt][r] * inv[r]);
            }
        }
    }
}

extern "C" void kernel_launch(void* const* d_in, const int* in_sizes, int n_in,
                              void* d_out, int out_size, void* d_ws, size_t ws_size,
                              hipStream_t stream) {
    const float* x       = (const float*)d_in[0];
    const float* Wq      = (const float*)d_in[1];
    const float* bq      = (const float*)d_in[2];
    const float* Wk      = (const float*)d_in[3];
    const float* bk      = (const float*)d_in[4];
    const float* Wv      = (const float*)d_in[5];
    const float* bv      = (const float*)d_in[6];
    const float* Wo      = (const float*)d_in[7];
    const float* bo      = (const float*)d_in[8];
    const float* q_tab_x = (const float*)d_in[9];
    const float* q_tab_y = (const float*)d_in[10];
    const float* v_tab_x = (const float*)d_in[11];
    const float* v_tab_y = (const float*)d_in[12];
    const int*   x_dist  = (const int*)d_in[13];
    const int*   y_dist  = (const int*)d_in[14];
    float* out = (float*)d_out;

    const int M  = in_sizes[0] / EMB;   // 12608
    const int Bc = M / SEQ;             // 64

    ushort* xb   = (ushort*)d_ws;
    ushort* wqkv = xb   + (size_t)M * EMB;
    ushort* wob  = wqkv + (size_t)2304 * EMB;
    ushort* xqb  = wob  + (size_t)EMB * EMB;
    ushort* xkb  = xqb  + (size_t)M * EMB;
    ushort* xvb  = xkb  + (size_t)M * EMB;
    ushort* aob  = xvb  + (size_t)M * EMB;
    ushort* r_o  = aob  + (size_t)M * EMB;

    const int n4x = M * EMB / 4;
    cvt_k<<<dim3((n4x + 255) / 256), dim3(256), 0, stream>>>(x, xb, n4x);
    cvt_w4<<<dim3(2304), dim3(256), 0, stream>>>(Wq, Wk, Wv, Wo, wqkv, wob);

    gemm_k64<0><<<dim3((M + 127) / 128, 18), dim3(256), 0, stream>>>(
        xb, wqkv, bq, bk, bv, xqb, xkb, xvb, nullptr, M);

    rxy_gemm<<<dim3(Bc * NH), dim3(256), 0, stream>>>(xqb, q_tab_x, q_tab_y, r_o);

    attn_mfma<<<dim3(Bc * NH), dim3(NT), 0, stream>>>(
        xqb, xkb, xvb, r_o, v_tab_x, v_tab_y, x_dist, y_dist, aob);

    gemm_k64<1><<<dim3((M + 127) / 128, 6), dim3(256), 0, stream>>>(
        aob, wob, bo, nullptr, nullptr, nullptr, nullptr, nullptr, out, M);
}

// Round 18
// 158.704 us; speedup vs baseline: 1.1785x; 1.1785x over previous
//
#include <hip/hip_runtime.h>
#include <math.h>

#define SEQ 197
#define EMB 768
#define NH  12
#define HD  64
#define NE  28
#define SK  208
#define VP  232
#define PP  232
#define EP  232
#define HP  66
#define TP  66
#define NW  7
#define NT  448

typedef __attribute__((ext_vector_type(8))) __bf16 bf16x8;
typedef __attribute__((ext_vector_type(4))) float  f32x4;

__device__ __forceinline__ unsigned short f2bf(float f) {
    unsigned u = __float_as_uint(f);
    u += 0x7fffu + ((u >> 16) & 1u);
    return (unsigned short)(u >> 16);
}
__device__ __forceinline__ float bfl(unsigned u) { return __uint_as_float(u << 16); }

__device__ __forceinline__ void gl_lds16(const ushort* g, ushort* l) {
    __builtin_amdgcn_global_load_lds(
        (const __attribute__((address_space(1))) unsigned int*)g,
        (__attribute__((address_space(3))) unsigned int*)l, 16, 0, 0);
}

// ---------------------------------------------------------------------------
// prep kernels
// ---------------------------------------------------------------------------
__global__ void cvt_k(const float* __restrict__ src, ushort* __restrict__ dst, int n4) {
    int i = blockIdx.x * 256 + threadIdx.x;
    if (i < n4) {
        float4 v = ((const float4*)src)[i];
        ushort4 o = { f2bf(v.x), f2bf(v.y), f2bf(v.z), f2bf(v.w) };
        ((ushort4*)dst)[i] = o;
    }
}

__global__ void cvt_w4(const float* __restrict__ wq, const float* __restrict__ wk,
                       const float* __restrict__ wv, const float* __restrict__ wo,
                       ushort* __restrict__ wqkv, ushort* __restrict__ wob) {
    int i = blockIdx.x * 256 + threadIdx.x;
    if (i >= 4 * 147456) return;
    int seg = i / 147456, r = i - seg * 147456;
    const float* s = (seg == 0) ? wq : (seg == 1) ? wk : (seg == 2) ? wv : wo;
    float4 v = ((const float4*)s)[r];
    ushort4 o = { f2bf(v.x), f2bf(v.y), f2bf(v.z), f2bf(v.w) };
    if (seg < 3) ((ushort4*)wqkv)[(size_t)seg * 147456 + r] = o;
    else         ((ushort4*)wob)[r] = o;
}

// ---------------------------------------------------------------------------
// rxy via tiny MFMA GEMM (r15) — unchanged.
// ---------------------------------------------------------------------------
__global__ __launch_bounds__(256) void rxy_gemm(
    const ushort* __restrict__ xq,
    const float* __restrict__ qtx, const float* __restrict__ qty,
    ushort* __restrict__ r_o)
{
    __shared__ __align__(16) ushort qtab_s[64][66];

    const int bh = blockIdx.x;
    const size_t base = (size_t)bh * SEQ * HD;
    const int tid = threadIdx.x;
    const int w = tid >> 6, lane = tid & 63;
    const int g = lane >> 4, c15 = lane & 15;

    for (int idx = tid; idx < 64 * 64; idx += 256) {
        const int e = idx >> 6, d = idx & 63;
        float v = 0.f;
        if (e < 28)      { if (d < 32)  v = qtx[e * 32 + d]; }
        else if (e < 56) { if (d >= 32) v = qty[(e - 28) * 32 + (d - 32)]; }
        qtab_s[e][d] = f2bf(v);
    }
    __syncthreads();

    for (int qt = w; qt < 13; qt += 4) {
        const int qrow = qt * 16 + c15;
        const int qld = (qrow < SEQ) ? qrow : SEQ - 1;
        const bf16x8 qa0 = *(const bf16x8*)(xq + base + (size_t)qld * HD + g * 8);
        const bf16x8 qa1 = *(const bf16x8*)(xq + base + (size_t)qld * HD + 32 + g * 8);
#pragma unroll
        for (int et = 0; et < 4; et++) {
            bf16x8 t0 = *(const bf16x8*)&qtab_s[et * 16 + c15][g * 8];
            bf16x8 t1 = *(const bf16x8*)&qtab_s[et * 16 + c15][32 + g * 8];
            f32x4 a = (f32x4)0.f;
            a = __builtin_amdgcn_mfma_f32_16x16x32_bf16(qa0, t0, a, 0, 0, 0);
            a = __builtin_amdgcn_mfma_f32_16x16x32_bf16(qa1, t1, a, 0, 0, 0);
#pragma unroll
            for (int r = 0; r < 4; r++) {
                const int q = qt * 16 + g * 4 + r;
                const int e = et * 16 + c15;
                if (q < SEQ && e < 56)
                    r_o[((size_t)bh * SEQ + q) * 56 + e] = f2bf(a[r]);
            }
        }
    }
}

// ---------------------------------------------------------------------------
// 128x128 GEMM, BK=64, SINGLE-buffer (r16 — reverted from r17's dbuf:
// 64 KB LDS halved blocks/CU 5->2 and cost 20 µs; cross-block TLP at
// 32 KB hides staging latency better than an intra-block pipeline).
// Swizzled staging: linear gl_lds dest + src chunk^(row&7), read ^(row&7).
// XCD-chunked grid swizzle. MODE 0: qkv scatter; MODE 1: fp32 out.
// ---------------------------------------------------------------------------
template<int MODE>
__global__ __launch_bounds__(256, 2) void gemm_k64(
    const ushort* __restrict__ A, const ushort* __restrict__ W,
    const float* __restrict__ b0, const float* __restrict__ b1, const float* __restrict__ b2,
    ushort* __restrict__ q_o, ushort* __restrict__ k_o, ushort* __restrict__ v_o,
    float* __restrict__ f_o, int M)
{
    __shared__ __align__(16) ushort As[128 * 64];   // 16 KB
    __shared__ __align__(16) ushort Bs[128 * 64];   // 16 KB

    const int tid  = threadIdx.x;
    const int w    = tid >> 6, lane = tid & 63;
    const int wr   = w >> 1,  wc   = w & 1;

    const int nmt = gridDim.x, nnt = gridDim.y;
    const int lin = blockIdx.y * nmt + blockIdx.x;
    const int gsz = 8 * nnt;
    const int grp = lin / gsz;
    const int rr  = lin - grp * gsz;
    int mig = nmt - grp * 8; if (mig > 8) mig = 8;
    const int mt  = grp * 8 + rr % mig;
    const int nt  = rr / mig;
    const int m0  = mt * 128;
    const int n0  = nt * 128;

    int arow[4], asrc[4];
#pragma unroll
    for (int i = 0; i < 4; i++) {
        const int gidx = tid + i * 256;
        const int row = gidx >> 3, ch = gidx & 7;
        arow[i] = row;
        asrc[i] = (ch ^ (row & 7)) * 8;
    }

    f32x4 acc[4][4];
#pragma unroll
    for (int m = 0; m < 4; m++)
#pragma unroll
        for (int n = 0; n < 4; n++) acc[m][n] = (f32x4)0.f;

    for (int k0 = 0; k0 < EMB; k0 += 64) {
#pragma unroll
        for (int i = 0; i < 4; i++) {
            int ra = m0 + arow[i]; if (ra >= M) ra = M - 1;
            gl_lds16(A + (size_t)ra * EMB + k0 + asrc[i], As + (tid + i * 256) * 8);
            gl_lds16(W + (size_t)(n0 + arow[i]) * EMB + k0 + asrc[i], Bs + (tid + i * 256) * 8);
        }
        __syncthreads();

#pragma unroll
        for (int kk = 0; kk < 2; kk++) {
            bf16x8 af[4], bfr[4];
#pragma unroll
            for (int m = 0; m < 4; m++) {
                const int row = wr * 64 + m * 16 + (lane & 15);
                af[m] = *(const bf16x8*)&As[row * 64 + (((kk * 4 + (lane >> 4)) ^ (row & 7)) << 3)];
            }
#pragma unroll
            for (int n = 0; n < 4; n++) {
                const int row = wc * 64 + n * 16 + (lane & 15);
                bfr[n] = *(const bf16x8*)&Bs[row * 64 + (((kk * 4 + (lane >> 4)) ^ (row & 7)) << 3)];
            }
#pragma unroll
            for (int m = 0; m < 4; m++)
#pragma unroll
                for (int n = 0; n < 4; n++)
                    acc[m][n] = __builtin_amdgcn_mfma_f32_16x16x32_bf16(af[m], bfr[n], acc[m][n], 0, 0, 0);
        }
        __syncthreads();
    }

    const int mat = n0 / EMB;
    const int nr  = n0 - mat * EMB;
    const float* bias = (mat == 0) ? b0 : (mat == 1) ? b1 : b2;
    ushort* dst = (mat == 0) ? q_o : (mat == 1) ? k_o : v_o;

#pragma unroll
    for (int m = 0; m < 4; m++) {
#pragma unroll
        for (int r = 0; r < 4; r++) {
            const int gm = m0 + wr * 64 + m * 16 + (lane >> 4) * 4 + r;
            if (gm >= M) continue;
            const int bb = gm / SEQ, ss = gm - bb * SEQ;
#pragma unroll
            for (int n = 0; n < 4; n++) {
                const int col = nr + wc * 64 + n * 16 + (lane & 15);
                if (MODE == 0) {
                    const float v = acc[m][n][r] + bias[col];
                    dst[(((size_t)bb * NH + (col >> 6)) * SEQ + ss) * HD + (col & 63)] = f2bf(v);
                } else {
                    f_o[(size_t)gm * EMB + col] = acc[m][n][r] + b0[col];
                }
            }
        }
    }
}

// ---------------------------------------------------------------------------
// MFMA fused attention (r12 one-hot factorization) + r17 latency trims:
// cx/cy staged packed in LDS; P_s pad-only zeroing; HP=66.
// ---------------------------------------------------------------------------
__global__ __launch_bounds__(NT) void attn_mfma(
    const ushort* __restrict__ xq, const ushort* __restrict__ xk, const ushort* __restrict__ xv,
    const ushort* __restrict__ rxy_g,
    const float* __restrict__ v_tab_x, const float* __restrict__ v_tab_y,
    const int* __restrict__ x_dist, const int* __restrict__ y_dist,
    ushort* __restrict__ ao)
{
    __shared__ __align__(16) ushort K_s[SK * HD];
    __shared__ __align__(16) ushort EXYs_s[SK * 40];
    __shared__ __align__(16) ushort EXYT_s[32 * EP];
    __shared__ __align__(16) ushort VT_s[HD * VP];
    __shared__ __align__(16) ushort P_s[NW * 16 * PP];
    __shared__ __align__(16) ushort vt_s[HD * TP];
    __shared__ __align__(16) ushort h_s[NW][16][HP];
    __shared__ ushort cxy_s[SEQ];

    const int bh = blockIdx.x;
    const int b  = bh / NH;
    const int h  = bh % NH;
    const size_t base = (size_t)bh * SEQ * HD;
    const ushort* __restrict__ rxy_b = rxy_g + (size_t)bh * SEQ * 56;
    const int tid = threadIdx.x;
    const int w = tid >> 6, lane = tid & 63;
    const int g = lane >> 4, c15 = lane & 15;

    for (int idx = tid; idx < SK * 8; idx += NT) {
        const int r = idx >> 3, c = idx & 7;
        uint4 v = make_uint4(0, 0, 0, 0);
        if (r < SEQ) v = *(const uint4*)(xk + base + r * HD + c * 8);
        *(uint4*)&K_s[r * HD + ((c ^ (r & 7)) << 3)] = v;
    }
    for (int idx = tid; idx < SK * 40 / 8; idx += NT)
        *(uint4*)&EXYs_s[idx * 8] = make_uint4(0, 0, 0, 0);
    for (int idx = tid; idx < 32 * EP / 8; idx += NT)
        *(uint4*)&EXYT_s[idx * 8] = make_uint4(0, 0, 0, 0);
    for (int idx = tid; idx < HD * (VP - SEQ); idx += NT) {
        const int d = idx / (VP - SEQ), k = SEQ + idx - d * (VP - SEQ);
        VT_s[d * VP + k] = 0;
    }
    for (int idx = tid; idx < NW * 16 * 3; idx += NT) {
        const int row = idx / 3, c = idx - row * 3;
        *(uint4*)&P_s[row * PP + 208 + c * 8] = make_uint4(0, 0, 0, 0);
    }
    for (int k = tid; k < SEQ; k += NT)
        cxy_s[k] = (ushort)((x_dist[SEQ + k] & 0xff) | ((y_dist[SEQ + k] & 0xff) << 8));
    for (int idx = tid; idx < 16 * 8 * 13; idx += NT) {
        const int kq = idx & 15, t = idx >> 4;
        const int db = t & 7, kh = t >> 3;
        const int k = kh * 16 + kq;
        if (k >= SEQ) continue;
        uint4 v = *(const uint4*)(xv + base + k * HD + db * 8);
        ushort* col = &VT_s[(db * 8) * VP + k];
        col[0 * VP] = (ushort)(v.x); col[1 * VP] = (ushort)(v.x >> 16);
        col[2 * VP] = (ushort)(v.y); col[3 * VP] = (ushort)(v.y >> 16);
        col[4 * VP] = (ushort)(v.z); col[5 * VP] = (ushort)(v.z >> 16);
        col[6 * VP] = (ushort)(v.w); col[7 * VP] = (ushort)(v.w >> 16);
    }
    for (int idx = tid; idx < HD * 64; idx += NT) {
        const int d = idx >> 6, e = idx & 63;
        float v = 0.f;
        if (d < 32) { if (e < 28) v = v_tab_x[e * 32 + d]; }
        else        { if (e >= 28 && e < 56) v = v_tab_y[(e - 28) * 32 + (d - 32)]; }
        vt_s[d * TP + e] = f2bf(v);
    }
    __syncthreads();
    for (int k = tid; k < SEQ; k += NT) {
        const int cx = (k == 0) ? 14 : ((cxy_s[k] & 0xff) - 14);
        const int cy = (k == 0) ? 14 : ((cxy_s[k] >> 8) - 14);
        const ushort one = 0x3f80;
        EXYs_s[k * 40 + cx]        = one;
        EXYs_s[k * 40 + 16 + cy]   = one;
        EXYT_s[cx * EP + k]        = one;
        EXYT_s[(16 + cy) * EP + k] = one;
    }
    __syncthreads();

    for (int qt = w; qt < 13; qt += NW) {
        const int qrow = qt * 16 + c15;
        const int qld  = (qrow < SEQ) ? qrow : (SEQ - 1);
        const bf16x8 qa0 = *(const bf16x8*)(xq + base + (size_t)qld * HD + g * 8);
        const bf16x8 qa1 = *(const bf16x8*)(xq + base + (size_t)qld * HD + 32 + g * 8);

        uint4 up;
        {
            const ushort* rrow = rxy_b + qld * 56;
            const int cxq = (qld > 0) ? ((cxy_s[qld] & 0xff) - 14) : 0;
            const int cyq = (qld > 0) ? ((cxy_s[qld] >> 8) - 14) : 0;
            unsigned uu[4] = {0, 0, 0, 0};
#pragma unroll
            for (int j = 0; j < 8; j++) {
                const int c = g * 8 + j;
                ushort v;
                if (qld == 0)      v = (c == 15 || c == 31) ? (ushort)0 : rrow[(c < 16) ? 0 : 28];
                else if (c < 14)   v = rrow[c - cxq + 14];
                else if (c == 14)  v = rrow[0];
                else if (c == 15)  v = 0;
                else if (c < 30)   v = rrow[28 + (c - 16) - cyq + 14];
                else if (c == 30)  v = rrow[28];
                else               v = 0;
                uu[j >> 1] |= ((unsigned)v) << ((j & 1) * 16);
            }
            up.x = uu[0]; up.y = uu[1]; up.z = uu[2]; up.w = uu[3];
        }
        const bf16x8 qa2 = *(bf16x8*)&up;

        {
            uint4* hz = (uint4*)h_s[w];
            for (int i = lane; i < 16 * HP / 8; i += 64) hz[i] = make_uint4(0, 0, 0, 0);
        }

        const int q4 = qt * 16 + 4 * g;
        float sum[4] = {0.f, 0.f, 0.f, 0.f};

#pragma unroll
        for (int kt = 0; kt < 13; kt++) {
            const int kr = kt * 16 + c15;
            bf16x8 kf0 = *(const bf16x8*)&K_s[kr * HD + (((0 + g) ^ (kr & 7)) << 3)];
            bf16x8 kf1 = *(const bf16x8*)&K_s[kr * HD + (((4 + g) ^ (kr & 7)) << 3)];
            bf16x8 kf2 = *(const bf16x8*)&EXYs_s[kr * 40 + g * 8];
            f32x4 a = (f32x4)0.f;
            a = __builtin_amdgcn_mfma_f32_16x16x32_bf16(qa0, kf0, a, 0, 0, 0);
            a = __builtin_amdgcn_mfma_f32_16x16x32_bf16(qa1, kf1, a, 0, 0, 0);
            a = __builtin_amdgcn_mfma_f32_16x16x32_bf16(qa2, kf2, a, 0, 0, 0);
#pragma unroll
            for (int r = 0; r < 4; r++) {
                const float l = a[r] * 0.125f - 8.0f;
                const float p = (kr < SEQ) ? __expf(l) : 0.f;
                sum[r] += p;
                P_s[(w * 16 + 4 * g + r) * PP + kr] = f2bf(p);
            }
        }
        float inv[4];
#pragma unroll
        for (int r = 0; r < 4; r++) {
            sum[r] += __shfl_xor(sum[r], 1);
            sum[r] += __shfl_xor(sum[r], 2);
            sum[r] += __shfl_xor(sum[r], 4);
            sum[r] += __shfl_xor(sum[r], 8);
            inv[r] = 1.f / sum[r];
        }

        f32x4 px0 = (f32x4)0.f, px1 = (f32x4)0.f;
#pragma unroll
        for (int ks = 0; ks < 7; ks++) {
            bf16x8 pf = *(const bf16x8*)&P_s[(w * 16 + c15) * PP + ks * 32 + g * 8];
            bf16x8 e0 = *(const bf16x8*)&EXYT_s[c15 * EP + ks * 32 + g * 8];
            bf16x8 e1 = *(const bf16x8*)&EXYT_s[(16 + c15) * EP + ks * 32 + g * 8];
            px0 = __builtin_amdgcn_mfma_f32_16x16x32_bf16(pf, e0, px0, 0, 0, 0);
            px1 = __builtin_amdgcn_mfma_f32_16x16x32_bf16(pf, e1, px1, 0, 0, 0);
        }

        float sx = px0[0], sy = px1[0];
        if (qt == 0) {
            sx += __shfl_xor(sx, 1); sx += __shfl_xor(sx, 2);
            sx += __shfl_xor(sx, 4); sx += __shfl_xor(sx, 8);
            sy += __shfl_xor(sy, 1); sy += __shfl_xor(sy, 2);
            sy += __shfl_xor(sy, 4); sy += __shfl_xor(sy, 8);
        }

#pragma unroll
        for (int r = 0; r < 4; r++) {
            const int q = q4 + r;
            if (q >= SEQ) continue;
            const int ql = 4 * g + r;
            if (q == 0) {
                if (c15 == 14) { h_s[w][ql][0] = f2bf(sx); h_s[w][ql][28] = f2bf(sy); }
            } else {
                const int cxq2 = (cxy_s[q] & 0xff) - 14;
                const int cyq2 = (cxy_s[q] >> 8) - 14;
                if (c15 < 14) {
                    h_s[w][ql][c15 - cxq2 + 14]      = f2bf(px0[r]);
                    h_s[w][ql][28 + c15 - cyq2 + 14] = f2bf(px1[r]);
                } else if (c15 == 14) {
                    h_s[w][ql][0]  = f2bf(px0[r]);
                    h_s[w][ql][28] = f2bf(px1[r]);
                }
            }
        }

        f32x4 o[4];
#pragma unroll
        for (int dt = 0; dt < 4; dt++) o[dt] = (f32x4)0.f;
#pragma unroll
        for (int ks = 0; ks < 7; ks++) {
            bf16x8 pf = *(const bf16x8*)&P_s[(w * 16 + c15) * PP + ks * 32 + g * 8];
#pragma unroll
            for (int dt = 0; dt < 4; dt++) {
                bf16x8 vf = *(const bf16x8*)&VT_s[(dt * 16 + c15) * VP + ks * 32 + g * 8];
                o[dt] = __builtin_amdgcn_mfma_f32_16x16x32_bf16(pf, vf, o[dt], 0, 0, 0);
            }
        }
#pragma unroll
        for (int ks2 = 0; ks2 < 2; ks2++) {
            bf16x8 hf = *(const bf16x8*)&h_s[w][c15][ks2 * 32 + g * 8];
#pragma unroll
            for (int dt = 0; dt < 4; dt++) {
                bf16x8 tf = *(const bf16x8*)&vt_s[(dt * 16 + c15) * TP + ks2 * 32 + g * 8];
                o[dt] = __builtin_amdgcn_mfma_f32_16x16x32_bf16(hf, tf, o[dt], 0, 0, 0);
            }
        }

#pragma unroll
        for (int dt = 0; dt < 4; dt++) {
            const int d = dt * 16 + c15;
#pragma unroll
            for (int r = 0; r < 4; r++) {
                const int q = q4 + r;
                if (q < SEQ)
                    ao[((size_t)(b * SEQ + q)) * EMB + h * HD + d] = f2bf(o[dt][r] * inv[r]);
            }
        }
    }
}

extern "C" void kernel_launch(void* const* d_in, const int* in_sizes, int n_in,
                              void* d_out, int out_size, void* d_ws, size_t ws_size,
                              hipStream_t stream) {
    const float* x       = (const float*)d_in[0];
    const float* Wq      = (const float*)d_in[1];
    const float* bq      = (const float*)d_in[2];
    const float* Wk      = (const float*)d_in[3];
    const float* bk      = (const float*)d_in[4];
    const float* Wv      = (const float*)d_in[5];
    const float* bv      = (const float*)d_in[6];
    const float* Wo      = (const float*)d_in[7];
    const float* bo      = (const float*)d_in[8];
    const float* q_tab_x = (const float*)d_in[9];
    const float* q_tab_y = (const float*)d_in[10];
    const float* v_tab_x = (const float*)d_in[11];
    const float* v_tab_y = (const float*)d_in[12];
    const int*   x_dist  = (const int*)d_in[13];
    const int*   y_dist  = (const int*)d_in[14];
    float* out = (float*)d_out;

    const int M  = in_sizes[0] / EMB;   // 12608
    const int Bc = M / SEQ;             // 64

    ushort* xb   = (ushort*)d_ws;
    ushort* wqkv = xb   + (size_t)M * EMB;
    ushort* wob  = wqkv + (size_t)2304 * EMB;
    ushort* xqb  = wob  + (size_t)EMB * EMB;
    ushort* xkb  = xqb  + (size_t)M * EMB;
    ushort* xvb  = xkb  + (size_t)M * EMB;
    ushort* aob  = xvb  + (size_t)M * EMB;
    ushort* r_o  = aob  + (size_t)M * EMB;

    const int n4x = M * EMB / 4;
    cvt_k<<<dim3((n4x + 255) / 256), dim3(256), 0, stream>>>(x, xb, n4x);
    cvt_w4<<<dim3(2304), dim3(256), 0, stream>>>(Wq, Wk, Wv, Wo, wqkv, wob);

    gemm_k64<0><<<dim3((M + 127) / 128, 18), dim3(256), 0, stream>>>(
        xb, wqkv, bq, bk, bv, xqb, xkb, xvb, nullptr, M);

    rxy_gemm<<<dim3(Bc * NH), dim3(256), 0, stream>>>(xqb, q_tab_x, q_tab_y, r_o);

    attn_mfma<<<dim3(Bc * NH), dim3(NT), 0, stream>>>(
        xqb, xkb, xvb, r_o, v_tab_x, v_tab_y, x_dist, y_dist, aob);

    gemm_k64<1><<<dim3((M + 127) / 128, 6), dim3(256), 0, stream>>>(
        aob, wob, bo, nullptr, nullptr, nullptr, nullptr, nullptr, out, M);
}